// Round 1
// baseline (413.667 us; speedup 1.0000x reference)
//
#include <hip/hip_runtime.h>

// DirectSolverNet forward (SOLVER_NO_DAMPING branch).
// Dominant cost: JtR = Jt @ (weights*R)  -> memory-bound, ~315 MB traffic.

__global__ __launch_bounds__(256) void jtr_kernel(
    const float* __restrict__ Jt,   // [B,6,N]
    const float* __restrict__ w,    // [B,N]
    const float* __restrict__ R,    // [B,N]
    float* __restrict__ JtR,        // [B,6] (pre-zeroed)
    int N) {
  const int b  = blockIdx.y;
  const int n0 = (blockIdx.x * 256 + threadIdx.x) * 4;
  if (n0 >= N) return;

  const float4 wv = *(const float4*)(w + (size_t)b * N + n0);
  const float4 rv = *(const float4*)(R + (size_t)b * N + n0);
  const float4 p  = make_float4(wv.x * rv.x, wv.y * rv.y, wv.z * rv.z, wv.w * rv.w);

  const float* jb = Jt + (size_t)b * 6 * N;
  float acc[6];
#pragma unroll
  for (int i = 0; i < 6; ++i) {
    const float4 jv = *(const float4*)(jb + (size_t)i * N + n0);
    acc[i] = jv.x * p.x + jv.y * p.y + jv.z * p.z + jv.w * p.w;
  }

  // wave64 shuffle reduction
#pragma unroll
  for (int i = 0; i < 6; ++i) {
    float v = acc[i];
#pragma unroll
    for (int off = 32; off > 0; off >>= 1)
      v += __shfl_down(v, off, 64);
    acc[i] = v;
  }

  __shared__ float part[4][6];
  const int lane = threadIdx.x & 63;
  const int wave = threadIdx.x >> 6;
  if (lane == 0) {
#pragma unroll
    for (int i = 0; i < 6; ++i) part[wave][i] = acc[i];
  }
  __syncthreads();
  if (threadIdx.x < 6) {
    float s = part[0][threadIdx.x] + part[1][threadIdx.x] +
              part[2][threadIdx.x] + part[3][threadIdx.x];
    atomicAdd(&JtR[b * 6 + threadIdx.x], s);
  }
}

__global__ __launch_bounds__(64) void solve_kernel(
    const float* __restrict__ JtJ,   // [B,6,6]
    const float* __restrict__ JtRg,  // [B,6]
    const float* __restrict__ R0,    // [B,3,3]
    const float* __restrict__ t0,    // [B,3,1]
    float* __restrict__ out,         // [B,3,4]
    int B) {
  const int b = blockIdx.x * 64 + threadIdx.x;
  if (b >= B) return;

  float H[6][6], rhs[6];
  float tr = 0.0f;
#pragma unroll
  for (int i = 0; i < 6; ++i) {
#pragma unroll
    for (int j = 0; j < 6; ++j) H[i][j] = JtJ[b * 36 + i * 6 + j];
    tr += H[i][i];
  }
  const float eps = tr * 1e-6f + 1e-6f;  // trace reg + inv_H's extra 1e-6*I
#pragma unroll
  for (int i = 0; i < 6; ++i) H[i][i] += eps;
#pragma unroll
  for (int i = 0; i < 6; ++i) rhs[i] = JtRg[b * 6 + i];

  // Gaussian elimination, no pivoting (H is SPD + reg)
#pragma unroll
  for (int k = 0; k < 6; ++k) {
    const float inv = 1.0f / H[k][k];
#pragma unroll
    for (int i = k + 1; i < 6; ++i) {
      const float f = H[i][k] * inv;
#pragma unroll
      for (int j = k + 1; j < 6; ++j) H[i][j] -= f * H[k][j];
      rhs[i] -= f * rhs[k];
    }
  }
  float xi[6];
#pragma unroll
  for (int i = 5; i >= 0; --i) {
    float s = rhs[i];
#pragma unroll
    for (int j = i + 1; j < 6; ++j) s -= H[i][j] * xi[j];
    xi[i] = s / H[i][i];
  }

  // d_R = exp(skew(-xi[:3])) via Rodrigues
  const float wx = -xi[0], wy = -xi[1], wz = -xi[2];
  const float th = sqrtf(wx * wx + wy * wy + wz * wz);
  const float safe = fmaxf(th, 1e-12f);
  const float a  = sinf(th) / safe;
  const float bb = (1.0f - cosf(th)) / (safe * safe);

  float K[3][3] = {{0.0f, -wz, wy}, {wz, 0.0f, -wx}, {-wy, wx, 0.0f}};
  float K2[3][3];
#pragma unroll
  for (int r = 0; r < 3; ++r)
#pragma unroll
    for (int c = 0; c < 3; ++c)
      K2[r][c] = K[r][0] * K[0][c] + K[r][1] * K[1][c] + K[r][2] * K[2][c];

  float dR[3][3];
#pragma unroll
  for (int r = 0; r < 3; ++r)
#pragma unroll
    for (int c = 0; c < 3; ++c)
      dR[r][c] = (r == c ? 1.0f : 0.0f) + a * K[r][c] + bb * K2[r][c];

  // d_t = -(d_R @ xi[3:])
  float dt[3];
#pragma unroll
  for (int r = 0; r < 3; ++r)
    dt[r] = -(dR[r][0] * xi[3] + dR[r][1] * xi[4] + dR[r][2] * xi[5]);

  // R_new = R0 @ d_R ; t_new = R0 @ d_t + t0
  const float* R0b = R0 + b * 9;
  const float* t0b = t0 + b * 3;
  float* ob = out + b * 12;
#pragma unroll
  for (int r = 0; r < 3; ++r) {
#pragma unroll
    for (int c = 0; c < 3; ++c) {
      ob[r * 4 + c] = R0b[r * 3 + 0] * dR[0][c] +
                      R0b[r * 3 + 1] * dR[1][c] +
                      R0b[r * 3 + 2] * dR[2][c];
    }
    ob[r * 4 + 3] = R0b[r * 3 + 0] * dt[0] +
                    R0b[r * 3 + 1] * dt[1] +
                    R0b[r * 3 + 2] * dt[2] + t0b[r];
  }
}

extern "C" void kernel_launch(void* const* d_in, const int* in_sizes, int n_in,
                              void* d_out, int out_size, void* d_ws, size_t ws_size,
                              hipStream_t stream) {
  const float* JtJ = (const float*)d_in[0];
  const float* Jt  = (const float*)d_in[1];
  const float* w   = (const float*)d_in[2];
  const float* R   = (const float*)d_in[3];
  const float* R0  = (const float*)d_in[4];
  const float* t0  = (const float*)d_in[5];
  float* out = (float*)d_out;

  const int B = in_sizes[0] / 36;          // 64
  const int N = in_sizes[1] / (6 * B);     // 153600

  float* JtR = (float*)d_ws;               // [B,6]
  hipMemsetAsync(JtR, 0, (size_t)B * 6 * sizeof(float), stream);

  const int elemsPerBlock = 256 * 4;
  dim3 grid((N + elemsPerBlock - 1) / elemsPerBlock, B);
  jtr_kernel<<<grid, 256, 0, stream>>>(Jt, w, R, JtR, N);

  solve_kernel<<<(B + 63) / 64, 64, 0, stream>>>(JtJ, JtR, R0, t0, out, B);
}

// Round 3
// 392.464 us; speedup vs baseline: 1.0540x; 1.0540x over previous
//
#include <hip/hip_runtime.h>

// DirectSolverNet forward (SOLVER_NO_DAMPING branch).
// Dominant cost: JtR = Jt @ (weights*R)  -> memory-bound, ~315 MB stream.
// N = 153600 is divisible by 2048 (elems per block); B = 64.

typedef float vfloat4 __attribute__((ext_vector_type(4)));

__global__ __launch_bounds__(256) void jtr_kernel(
    const float* __restrict__ Jt,   // [B,6,N]
    const float* __restrict__ w,    // [B,N]
    const float* __restrict__ R,    // [B,N]
    float* __restrict__ part,       // [B, gx, 6] per-block partials
    int N, int gx) {
  const int b    = blockIdx.y;
  const int base = blockIdx.x * 2048;           // 256 threads * 8 floats
  const int t4   = threadIdx.x * 4;
  const size_t bN = (size_t)b * N;
  const int n0 = base + t4;                     // first coalesced float4
  const int n1 = base + 1024 + t4;              // second coalesced float4

  const vfloat4 w0 = __builtin_nontemporal_load((const vfloat4*)(w + bN + n0));
  const vfloat4 w1 = __builtin_nontemporal_load((const vfloat4*)(w + bN + n1));
  const vfloat4 r0 = __builtin_nontemporal_load((const vfloat4*)(R + bN + n0));
  const vfloat4 r1 = __builtin_nontemporal_load((const vfloat4*)(R + bN + n1));
  const vfloat4 p0 = w0 * r0;
  const vfloat4 p1 = w1 * r1;

  const float* jb = Jt + bN * 6;
  float acc[6];
#pragma unroll
  for (int i = 0; i < 6; ++i) {
    const vfloat4 j0 = __builtin_nontemporal_load((const vfloat4*)(jb + (size_t)i * N + n0));
    const vfloat4 j1 = __builtin_nontemporal_load((const vfloat4*)(jb + (size_t)i * N + n1));
    const vfloat4 s = j0 * p0 + j1 * p1;
    acc[i] = s.x + s.y + s.z + s.w;
  }

  // wave64 shuffle reduction
#pragma unroll
  for (int i = 0; i < 6; ++i) {
    float v = acc[i];
#pragma unroll
    for (int off = 32; off > 0; off >>= 1)
      v += __shfl_down(v, off, 64);
    acc[i] = v;
  }

  __shared__ float ws[4][6];
  const int lane = threadIdx.x & 63;
  const int wave = threadIdx.x >> 6;
  if (lane == 0) {
#pragma unroll
    for (int i = 0; i < 6; ++i) ws[wave][i] = acc[i];
  }
  __syncthreads();
  if (threadIdx.x < 6) {
    part[((size_t)b * gx + blockIdx.x) * 6 + threadIdx.x] =
        ws[0][threadIdx.x] + ws[1][threadIdx.x] +
        ws[2][threadIdx.x] + ws[3][threadIdx.x];
  }
}

// One block per batch: reduce partials, then thread 0 does the 6x6 solve,
// Rodrigues, and pose compose (a few hundred FLOPs).
__global__ __launch_bounds__(64) void solve_kernel(
    const float* __restrict__ JtJ,   // [B,6,6]
    const float* __restrict__ part,  // [B, gx, 6]
    const float* __restrict__ R0,    // [B,3,3]
    const float* __restrict__ t0,    // [B,3,1]
    float* __restrict__ out,         // [B,3,4]
    int gx) {
  const int b = blockIdx.x;
  const int t = threadIdx.x;
  __shared__ float lds[10][6];
  __shared__ float jtr[6];

  if (t < 60) {
    const int r = t % 6, k = t / 6;
    float s = 0.0f;
    for (int j = k; j < gx; j += 10)
      s += part[((size_t)b * gx + j) * 6 + r];
    lds[k][r] = s;
  }
  __syncthreads();
  if (t < 6) {
    float s = 0.0f;
#pragma unroll
    for (int k = 0; k < 10; ++k) s += lds[k][t];
    jtr[t] = s;
  }
  __syncthreads();
  if (t != 0) return;

  float H[6][6], rhs[6];
  float trace = 0.0f;
#pragma unroll
  for (int i = 0; i < 6; ++i) {
#pragma unroll
    for (int j = 0; j < 6; ++j) H[i][j] = JtJ[b * 36 + i * 6 + j];
    trace += H[i][i];
  }
  const float eps = trace * 1e-6f + 1e-6f;  // trace reg + inv_H's extra 1e-6*I
#pragma unroll
  for (int i = 0; i < 6; ++i) H[i][i] += eps;
#pragma unroll
  for (int i = 0; i < 6; ++i) rhs[i] = jtr[i];

  // Gaussian elimination, no pivoting (H is SPD + reg)
#pragma unroll
  for (int k = 0; k < 6; ++k) {
    const float inv = 1.0f / H[k][k];
#pragma unroll
    for (int i = k + 1; i < 6; ++i) {
      const float f = H[i][k] * inv;
#pragma unroll
      for (int j = k + 1; j < 6; ++j) H[i][j] -= f * H[k][j];
      rhs[i] -= f * rhs[k];
    }
  }
  float xi[6];
#pragma unroll
  for (int i = 5; i >= 0; --i) {
    float s = rhs[i];
#pragma unroll
    for (int j = i + 1; j < 6; ++j) s -= H[i][j] * xi[j];
    xi[i] = s / H[i][i];
  }

  // d_R = exp(skew(-xi[:3])) via Rodrigues
  const float wx = -xi[0], wy = -xi[1], wz = -xi[2];
  const float th = sqrtf(wx * wx + wy * wy + wz * wz);
  const float safe = fmaxf(th, 1e-12f);
  const float a  = sinf(th) / safe;
  const float bb = (1.0f - cosf(th)) / (safe * safe);

  const float K[3][3] = {{0.0f, -wz, wy}, {wz, 0.0f, -wx}, {-wy, wx, 0.0f}};
  float K2[3][3];
#pragma unroll
  for (int r = 0; r < 3; ++r)
#pragma unroll
    for (int c = 0; c < 3; ++c)
      K2[r][c] = K[r][0] * K[0][c] + K[r][1] * K[1][c] + K[r][2] * K[2][c];

  float dR[3][3];
#pragma unroll
  for (int r = 0; r < 3; ++r)
#pragma unroll
    for (int c = 0; c < 3; ++c)
      dR[r][c] = (r == c ? 1.0f : 0.0f) + a * K[r][c] + bb * K2[r][c];

  float dt[3];
#pragma unroll
  for (int r = 0; r < 3; ++r)
    dt[r] = -(dR[r][0] * xi[3] + dR[r][1] * xi[4] + dR[r][2] * xi[5]);

  const float* R0b = R0 + b * 9;
  const float* t0b = t0 + b * 3;
  float* ob = out + b * 12;
#pragma unroll
  for (int r = 0; r < 3; ++r) {
#pragma unroll
    for (int c = 0; c < 3; ++c) {
      ob[r * 4 + c] = R0b[r * 3 + 0] * dR[0][c] +
                      R0b[r * 3 + 1] * dR[1][c] +
                      R0b[r * 3 + 2] * dR[2][c];
    }
    ob[r * 4 + 3] = R0b[r * 3 + 0] * dt[0] +
                    R0b[r * 3 + 1] * dt[1] +
                    R0b[r * 3 + 2] * dt[2] + t0b[r];
  }
}

extern "C" void kernel_launch(void* const* d_in, const int* in_sizes, int n_in,
                              void* d_out, int out_size, void* d_ws, size_t ws_size,
                              hipStream_t stream) {
  const float* JtJ = (const float*)d_in[0];
  const float* Jt  = (const float*)d_in[1];
  const float* w   = (const float*)d_in[2];
  const float* R   = (const float*)d_in[3];
  const float* R0  = (const float*)d_in[4];
  const float* t0  = (const float*)d_in[5];
  float* out = (float*)d_out;

  const int B = in_sizes[0] / 36;          // 64
  const int N = in_sizes[1] / (6 * B);     // 153600 (divisible by 2048)
  const int gx = N / 2048;                 // 75 blocks along n

  float* part = (float*)d_ws;              // [B, gx, 6] partials (fully overwritten)

  dim3 grid(gx, B);
  jtr_kernel<<<grid, 256, 0, stream>>>(Jt, w, R, part, N, gx);
  solve_kernel<<<B, 64, 0, stream>>>(JtJ, part, R0, t0, out, gx);
}